// Round 7
// baseline (1033.126 us; speedup 1.0000x reference)
//
#include <hip/hip_runtime.h>
#include <math.h>

// Problem constants
#define T_LEN  256
#define BATCH  32
#define EMBD   256
#define HHD    256           // per-direction hidden
#define NTAGS  12
#define NEGV   (-10000.0f)

// R7: AGPR pins. "+v" pins (R6) failed: VGPR_Count stayed 104 (< the 128
// needed), i.e. the allocator kept W in memory and re-streamed it from L2
// every step (256KB/CU/step / ~144GB/s/CU = 1.8us = the measured 2.0us step
// floor). "+a" forces the 128 W components into ACCUMULATOR registers:
// gfx950's unified file gives ~512 regs/wave, AGPR values cannot be
// rematerialized from global, and arch-VGPR pressure stays ~104 -> the
// cheapest legal allocation is true residency. VALU reads AGPRs directly
// (VOP3 v256-511) or via v_accvgpr_read temps - either is ~100x cheaper
// than the L2 stream.
#define PIN4(r0,r1,r2,r3)                                                  \
    asm volatile("" : "+a"(r0.x),"+a"(r0.y),"+a"(r0.z),"+a"(r0.w),         \
                      "+a"(r1.x),"+a"(r1.y),"+a"(r1.z),"+a"(r1.w),         \
                      "+a"(r2.x),"+a"(r2.y),"+a"(r2.z),"+a"(r2.w),         \
                      "+a"(r3.x),"+a"(r3.y),"+a"(r3.z),"+a"(r3.w))

#define PIN_ALL_W() do {                                                   \
    PIN4(wreg[0],wreg[1],wreg[2],wreg[3]);                                 \
    PIN4(wreg[4],wreg[5],wreg[6],wreg[7]);                                 \
    PIN4(wreg[8],wreg[9],wreg[10],wreg[11]);                               \
    PIN4(wreg[12],wreg[13],wreg[14],wreg[15]);                             \
    PIN4(wreg[16],wreg[17],wreg[18],wreg[19]);                             \
    PIN4(wreg[20],wreg[21],wreg[22],wreg[23]);                             \
    PIN4(wreg[24],wreg[25],wreg[26],wreg[27]);                             \
    PIN4(wreg[28],wreg[29],wreg[30],wreg[31]);                             \
} while (0)

// ---------------------------------------------------------------------------
// Kernel 1: zx = gather(embed)[m,:] @ [W_ih_f | W_ih_b]^T + bias
// M = 8192 rows (m = t*32 + b), N = 2048, K = 256. 128x128x16 tile.
// ---------------------------------------------------------------------------
__global__ __launch_bounds__(256) void gemm_zx(
    const int* __restrict__ sentence, const float* __restrict__ embed,
    const float* __restrict__ Wf,  const float* __restrict__ Wb,
    const float* __restrict__ bf,  const float* __restrict__ bb,
    float* __restrict__ zx)
{
    __shared__ float As[16][132];
    __shared__ float Bs[16][132];

    const int tid = threadIdx.x;
    const int tx = tid & 15, ty = tid >> 4;
    const int Mbase = (int)(blockIdx.x >> 4) * 128;
    const int Nbase = (int)(blockIdx.x & 15) * 128;

    const float* Wsrc = (Nbase < 1024) ? Wf : Wb;
    const float* bsrc = (Nbase < 1024) ? bf : bb;
    const int nOff = (Nbase < 1024) ? Nbase : (Nbase - 1024);

    const int m0 = tid >> 2;
    const int m1 = m0 + 64;
    const int kq = (tid & 3) * 4;
    const int mg0 = Mbase + m0, mg1 = Mbase + m1;
    const int tok0 = sentence[(mg0 & 31) * T_LEN + (mg0 >> 5)];
    const int tok1 = sentence[(mg1 & 31) * T_LEN + (mg1 >> 5)];
    const float* arow0 = embed + (long long)tok0 * EMBD;
    const float* arow1 = embed + (long long)tok1 * EMBD;
    const float* brow0 = Wsrc + (long long)(nOff + m0) * EMBD;
    const float* brow1 = Wsrc + (long long)(nOff + m1) * EMBD;

    float acc[8][8];
#pragma unroll
    for (int i = 0; i < 8; ++i)
#pragma unroll
        for (int j = 0; j < 8; ++j) acc[i][j] = 0.0f;

    for (int k0 = 0; k0 < EMBD; k0 += 16) {
        float4 av0 = *(const float4*)(arow0 + k0 + kq);
        float4 av1 = *(const float4*)(arow1 + k0 + kq);
        float4 bv0 = *(const float4*)(brow0 + k0 + kq);
        float4 bv1 = *(const float4*)(brow1 + k0 + kq);
        __syncthreads();
        As[kq+0][m0] = av0.x; As[kq+1][m0] = av0.y; As[kq+2][m0] = av0.z; As[kq+3][m0] = av0.w;
        As[kq+0][m1] = av1.x; As[kq+1][m1] = av1.y; As[kq+2][m1] = av1.z; As[kq+3][m1] = av1.w;
        Bs[kq+0][m0] = bv0.x; Bs[kq+1][m0] = bv0.y; Bs[kq+2][m0] = bv0.z; Bs[kq+3][m0] = bv0.w;
        Bs[kq+0][m1] = bv1.x; Bs[kq+1][m1] = bv1.y; Bs[kq+2][m1] = bv1.z; Bs[kq+3][m1] = bv1.w;
        __syncthreads();
#pragma unroll
        for (int kt = 0; kt < 16; ++kt) {
            float am[8], bn[8];
            *(float4*)&am[0] = *(const float4*)&As[kt][ty * 4];
            *(float4*)&am[4] = *(const float4*)&As[kt][64 + ty * 4];
            *(float4*)&bn[0] = *(const float4*)&Bs[kt][tx * 4];
            *(float4*)&bn[4] = *(const float4*)&Bs[kt][64 + tx * 4];
#pragma unroll
            for (int i = 0; i < 8; ++i)
#pragma unroll
                for (int j = 0; j < 8; ++j) acc[i][j] += am[i] * bn[j];
        }
    }

    float4 bias0 = *(const float4*)(bsrc + nOff + tx * 4);
    float4 bias1 = *(const float4*)(bsrc + nOff + 64 + tx * 4);
    const float bnv[8] = {bias0.x, bias0.y, bias0.z, bias0.w,
                          bias1.x, bias1.y, bias1.z, bias1.w};
#pragma unroll
    for (int i = 0; i < 8; ++i) {
        const int mg = Mbase + ty * 4 + (i & 3) + ((i >= 4) ? 64 : 0);
        float4 o0 = make_float4(acc[i][0] + bnv[0], acc[i][1] + bnv[1],
                                acc[i][2] + bnv[2], acc[i][3] + bnv[3]);
        float4 o1 = make_float4(acc[i][4] + bnv[4], acc[i][5] + bnv[5],
                                acc[i][6] + bnv[6], acc[i][7] + bnv[7]);
        *(float4*)(zx + (long long)mg * 2048 + Nbase + tx * 4) = o0;
        *(float4*)(zx + (long long)mg * 2048 + Nbase + 64 + tx * 4) = o1;
    }
}

// ---------------------------------------------------------------------------
// Kernel 1b: pack W_hh into per-(slice,thread) contiguous 512 B chunks:
// offset = (((d*4+q)*2 + half)*256 + j)*128 + k2
//   j = gate-row within WG (g = j>>6, e = q*64 + (j&63)), k = half*128+k2.
// lstm_team WG with slice sl = d*4+q, thread tid reads chunk at tid*128.
// ---------------------------------------------------------------------------
__global__ __launch_bounds__(256) void pack_whh(
    const float* __restrict__ Whf, const float* __restrict__ Whb,
    float* __restrict__ pack)
{
    const int gid = blockIdx.x * 256 + threadIdx.x;   // 0..524287
    const int k2   = gid & 127;
    const int j    = (gid >> 7) & 255;
    const int half = (gid >> 15) & 1;
    const int q    = (gid >> 16) & 3;
    const int d    = (gid >> 18) & 1;
    const float* W = d ? Whb : Whf;
    const int g = j >> 6;
    const int e = q * 64 + (j & 63);
    pack[gid] = W[(g * 256 + e) * 256 + half * 128 + k2];
}

// ---------------------------------------------------------------------------
// Kernel 2: REGISTER-RESIDENT team LSTM.  256 WGs x 512 threads.
// R7: identical to R6 except the W pins target AGPRs ("+a") instead of
// arch VGPRs. R6 proved (VGPR_Count=104 < 128 needed) that "+v" pinning
// was defeated and W re-streamed from L2 each step (1.8us of the 2.0us
// step). AGPR residency removes the stream; dot reads AGPRs directly
// (VOP3) or via v_accvgpr_read temps (~130cy/step extra VALU, cheap).
// Exchange: R0-proven single agent-scope channel. zx prefetched one full
// step ahead. Plain __syncthreads() barriers.
// VERIFY next counters: register count ~230 (or VGPR 104 + AGPR 128 if
// reported separately); lstm_team < 400us, else AGPR path also defeated.
// ---------------------------------------------------------------------------
__global__ __launch_bounds__(512, 1) void lstm_team(
    const float* __restrict__ zx, const float* __restrict__ pack,
    const float* __restrict__ h0, const float* __restrict__ c0,
    unsigned long long* __restrict__ hx,   // [2 par][2 d][32 b][256 e]
    float* __restrict__ lstm_out)
{
    __shared__ float hS0[256];
    __shared__ float hS1[256];
    __shared__ float pS[512];

    const int tid = threadIdx.x;
    const int bx  = (int)blockIdx.x;
    const int b  = ((bx >> 5) & 3) * 8 + (bx & 7);
    const int q  = (bx >> 3) & 3;
    const int d  = (bx >> 7) & 1;
    const int sl = d * 4 + q;

    // --- W half-row into registers (one-time, coalesced), then into AGPRs ---
    float4 wreg[32];
    {
        const float4* wrow = (const float4*)(pack + ((long long)sl << 16)
                                             + tid * 128);
#pragma unroll
        for (int c = 0; c < 32; ++c) wreg[c] = wrow[c];
    }
    PIN_ALL_W();

    const int half = tid >> 8;            // k-half this thread dots
    const long long hxbase = (long long)(d * 32 + b) * 256;
    float creg = (tid < 64) ? c0[(d * 32 + b) * 256 + q * 64 + tid] : 0.0f;

    if (tid < 256) hS0[tid] = h0[(d * 32 + b) * 256 + tid];
    __syncthreads();

    // zx pipeline: current step's 4 gate pre-activations, one step ahead
    const int zco = d * 1024 + q * 64 + (tid & 63);
    float zv0 = 0.f, zv1 = 0.f, zv2 = 0.f, zv3 = 0.f;
    if (tid < 64) {
        const int t0 = d ? (T_LEN - 1) : 0;
        const float* zr = zx + (long long)(t0 * 32 + b) * 2048 + zco;
        zv0 = zr[0]; zv1 = zr[256]; zv2 = zr[512]; zv3 = zr[768];
    }

    for (int s = 0; s < T_LEN; ++s) {
        PIN_ALL_W();                       // per-step AGPR residency
        const int t = d ? (T_LEN - 1 - s) : s;

        // prefetch NEXT step's zx (full step of latency slack)
        float zn0 = zv0, zn1 = zv1, zn2 = zv2, zn3 = zv3;
        if (tid < 64 && s < T_LEN - 1) {
            const int tn = d ? (T_LEN - 2 - s) : (s + 1);
            const float* zr = zx + (long long)(tn * 32 + b) * 2048 + zco;
            zn0 = zr[0]; zn1 = zr[256]; zn2 = zr[512]; zn3 = zr[768];
        }

        const float* h  = (s & 1) ? hS1 : hS0;
        float*       hN = (s & 1) ? hS0 : hS1;
        const float* hh = h + half * 128;   // wave-uniform -> LDS broadcast

        // --- half-dot from AGPR-resident W ---
        float a = 0.0f;
#pragma unroll
        for (int c = 0; c < 32; ++c) {
            const float4 hv = *(const float4*)(hh + c * 4);
            a += wreg[c].x * hv.x + wreg[c].y * hv.y
               + wreg[c].z * hv.z + wreg[c].w * hv.w;
        }
        pS[tid] = a;
        __syncthreads();

        const int parN = (s & 1) ^ 1;
        if (tid < 64) {
            const float zi = pS[tid]       + pS[tid + 256] + zv0;
            const float zf = pS[tid + 64]  + pS[tid + 320] + zv1;
            const float zg = pS[tid + 128] + pS[tid + 384] + zv2;
            const float zo = pS[tid + 192] + pS[tid + 448] + zv3;
            const float si = 1.0f / (1.0f + expf(-zi));
            const float sf = 1.0f / (1.0f + expf(-zf));
            const float so = 1.0f / (1.0f + expf(-zo));
            creg = sf * creg + si * tanhf(zg);
            const float hn = so * tanhf(creg);
            const int e = q * 64 + tid;
            hN[e] = hn;
            lstm_out[(long long)(t * 32 + b) * 512 + d * 256 + e] = hn;
            __hip_atomic_store(hx + (long long)parN * 16384 + hxbase + e,
                ((unsigned long long)(unsigned)(s + 1) << 32)
                    | (unsigned long long)__float_as_uint(hn),
                __ATOMIC_RELAXED, __HIP_MEMORY_SCOPE_AGENT);
        } else if (s < T_LEN - 1) {
            int e = -1;
            if (tid < 256) { if ((tid >> 6) != q) e = tid; }
            else if (tid < 320) { if (q != 0) e = tid - 256; }
            if (e >= 0) {
                const unsigned long long* slot =
                    hx + (long long)parN * 16384 + hxbase + e;
                unsigned long long v;
                do {
                    v = __hip_atomic_load(slot, __ATOMIC_RELAXED,
                                          __HIP_MEMORY_SCOPE_AGENT);
                } while ((unsigned)(v >> 32) != (unsigned)(s + 1));
                hN[e] = __uint_as_float((unsigned)v);
            }
        }
        zv0 = zn0; zv1 = zn1; zv2 = zn2; zv3 = zn3;
        __syncthreads();
    }
}

// ---------------------------------------------------------------------------
// Kernel 3: feats = lstm_out @ W_out^T + b_out
// ---------------------------------------------------------------------------
__global__ __launch_bounds__(256) void feats_kernel(
    const float* __restrict__ lstm_out, const float* __restrict__ W_out,
    const float* __restrict__ b_out, float* __restrict__ feats)
{
    const int gid = blockIdx.x * 256 + threadIdx.x;
    if (gid >= 8192 * NTAGS) return;
    const int row = gid / NTAGS;
    const int tag = gid - row * NTAGS;
    const float4* x = (const float4*)(lstm_out + (long long)row * 512);
    const float4* w = (const float4*)(W_out + (long long)tag * 512);
    float acc = b_out[tag];
#pragma unroll 4
    for (int k = 0; k < 128; ++k) {
        float4 a = x[k], bw = w[k];
        acc += a.x * bw.x + a.y * bw.y + a.z * bw.z + a.w * bw.w;
    }
    const int t = row >> 5, b = row & 31;
    feats[(long long)b * (T_LEN * NTAGS) + t * NTAGS + tag] = acc;
}

// ---------------------------------------------------------------------------
// Kernel 4: Viterbi per batch. 32 WGs x 64 threads.
// ---------------------------------------------------------------------------
__global__ __launch_bounds__(64) void viterbi_kernel(
    const float* __restrict__ feats, const float* __restrict__ trans,
    float* __restrict__ out)
{
    __shared__ float featS[T_LEN * NTAGS];
    __shared__ float transS[NTAGS * NTAGS];
    __shared__ float fvS[NTAGS];
    __shared__ unsigned char bpS[T_LEN][NTAGS];
    __shared__ float pathS[T_LEN];

    const int b = blockIdx.x;
    const int lane = threadIdx.x;

    {
        const float4* src = (const float4*)(feats + (long long)b * (T_LEN * NTAGS));
        float4* dst = (float4*)featS;
        for (int i = lane; i < (T_LEN * NTAGS) / 4; i += 64) dst[i] = src[i];
        for (int i = lane; i < NTAGS * NTAGS; i += 64) transS[i] = trans[i];
    }
    __syncthreads();

    float fv[NTAGS];
#pragma unroll
    for (int p = 0; p < NTAGS; ++p) fv[p] = (p == 10) ? 0.0f : NEGV;

    for (int t = 0; t < T_LEN; ++t) {
        if (lane < NTAGS) {
            float best = -3.4e38f; int bi = 0;
#pragma unroll
            for (int p = 0; p < NTAGS; ++p) {
                const float v = fv[p] + transS[lane * NTAGS + p];
                if (v > best) { best = v; bi = p; }
            }
            bpS[t][lane] = (unsigned char)bi;
            fvS[lane] = best + featS[t * NTAGS + lane];
        }
        __syncthreads();
#pragma unroll
        for (int p = 0; p < NTAGS; ++p) fv[p] = fvS[p];
        __syncthreads();
    }

    if (lane < NTAGS) fvS[lane] = fv[lane] + transS[11 * NTAGS + lane];
    __syncthreads();
    if (lane == 0) {
        float best = -3.4e38f; int bi = 0;
        for (int p = 0; p < NTAGS; ++p) {
            const float v = fvS[p];
            if (v > best) { best = v; bi = p; }
        }
        out[b] = best;
        int cur = bi;
        pathS[T_LEN - 1] = (float)cur;
        for (int tt = T_LEN - 2; tt >= 0; --tt) {
            cur = bpS[tt + 1][cur];
            pathS[tt] = (float)cur;
        }
    }
    __syncthreads();
    float* po = out + BATCH + (long long)b * T_LEN;
    for (int i = lane; i < T_LEN; i += 64) po[i] = pathS[i];
}

// ---------------------------------------------------------------------------
extern "C" void kernel_launch(void* const* d_in, const int* in_sizes, int n_in,
                              void* d_out, int out_size, void* d_ws, size_t ws_size,
                              hipStream_t stream)
{
    (void)in_sizes; (void)n_in; (void)out_size; (void)ws_size;
    const int*   sentence = (const int*)  d_in[0];
    const float* embed    = (const float*)d_in[1];
    const float* W_ih_f   = (const float*)d_in[2];
    const float* W_hh_f   = (const float*)d_in[3];
    const float* b_f      = (const float*)d_in[4];
    const float* W_ih_b   = (const float*)d_in[5];
    const float* W_hh_b   = (const float*)d_in[6];
    const float* b_b      = (const float*)d_in[7];
    const float* W_out    = (const float*)d_in[8];
    const float* b_out    = (const float*)d_in[9];
    const float* trans    = (const float*)d_in[10];
    const float* h0       = (const float*)d_in[11];
    const float* c0       = (const float*)d_in[12];
    float* out = (float*)d_out;

    char* ws = (char*)d_ws;
    float* zx       = (float*)ws; ws += (long long)8192 * 2048 * 4;   // 64 MB
    float* lstm_out = (float*)ws; ws += (long long)8192 * 512 * 4;    // 16 MB
    float* feats    = (float*)ws; ws += BATCH * T_LEN * NTAGS * 4;    // 384 KB
    float* pack     = (float*)ws; ws += (long long)524288 * 4;        // 2 MB
    unsigned long long* hx = (unsigned long long*)ws; ws += 2 * 16384 * 8; // 256 KB
    // hx re-poisoned to 0xAA before every launch -> tags invalid. No memset.

    pack_whh<<<2048, 256, 0, stream>>>(W_hh_f, W_hh_b, pack);
    gemm_zx<<<1024, 256, 0, stream>>>(sentence, embed, W_ih_f, W_ih_b, b_f, b_b, zx);
    lstm_team<<<256, 512, 0, stream>>>(zx, pack, h0, c0, hx, lstm_out);
    feats_kernel<<<384, 256, 0, stream>>>(lstm_out, W_out, b_out, feats);
    viterbi_kernel<<<32, 64, 0, stream>>>(feats, trans, out);
}

// Round 8
// 824.872 us; speedup vs baseline: 1.2525x; 1.2525x over previous
//
#include <hip/hip_runtime.h>
#include <math.h>

// Problem constants
#define T_LEN  256
#define BATCH  32
#define EMBD   256
#define HHD    256           // per-direction hidden
#define NTAGS  12
#define NEGV   (-10000.0f)

// R8: one-time AGPR pin (NOT per-iteration - R7 proved per-iteration "+a"
// pins cost ~1400cy/step of AGPR<->VGPR copies). asm-defined AGPR values
// cannot be rematerialized from global; launch_bounds(512,2) caps unified
// regs at 256 so 128 AGPR W + ~70 VGPR fits at 2 waves/SIMD.
#define PINA4(r0,r1,r2,r3)                                                 \
    asm volatile("" : "+a"(r0.x),"+a"(r0.y),"+a"(r0.z),"+a"(r0.w),         \
                      "+a"(r1.x),"+a"(r1.y),"+a"(r1.z),"+a"(r1.w),         \
                      "+a"(r2.x),"+a"(r2.y),"+a"(r2.z),"+a"(r2.w),         \
                      "+a"(r3.x),"+a"(r3.y),"+a"(r3.z),"+a"(r3.w))

// 16-lane (DPP row) sum: lane (16k) accumulates lanes 16k..16k+15.
__device__ __forceinline__ float dpp_add16(float x) {
    int t;
    t = __builtin_amdgcn_update_dpp(0, __float_as_int(x), 0x118, 0xf, 0xf, true);
    x += __int_as_float(t);
    t = __builtin_amdgcn_update_dpp(0, __float_as_int(x), 0x114, 0xf, 0xf, true);
    x += __int_as_float(t);
    t = __builtin_amdgcn_update_dpp(0, __float_as_int(x), 0x112, 0xf, 0xf, true);
    x += __int_as_float(t);
    t = __builtin_amdgcn_update_dpp(0, __float_as_int(x), 0x111, 0xf, 0xf, true);
    x += __int_as_float(t);
    return x;
}

// ---------------------------------------------------------------------------
// Kernel 1: zx = gather(embed)[m,:] @ [W_ih_f | W_ih_b]^T + bias
// M = 8192 rows (m = t*32 + b), N = 2048, K = 256. 128x128x16 tile. (R6)
// ---------------------------------------------------------------------------
__global__ __launch_bounds__(256) void gemm_zx(
    const int* __restrict__ sentence, const float* __restrict__ embed,
    const float* __restrict__ Wf,  const float* __restrict__ Wb,
    const float* __restrict__ bf,  const float* __restrict__ bb,
    float* __restrict__ zx)
{
    __shared__ float As[16][132];
    __shared__ float Bs[16][132];

    const int tid = threadIdx.x;
    const int tx = tid & 15, ty = tid >> 4;
    const int Mbase = (int)(blockIdx.x >> 4) * 128;
    const int Nbase = (int)(blockIdx.x & 15) * 128;

    const float* Wsrc = (Nbase < 1024) ? Wf : Wb;
    const float* bsrc = (Nbase < 1024) ? bf : bb;
    const int nOff = (Nbase < 1024) ? Nbase : (Nbase - 1024);

    const int m0 = tid >> 2;
    const int m1 = m0 + 64;
    const int kq = (tid & 3) * 4;
    const int mg0 = Mbase + m0, mg1 = Mbase + m1;
    const int tok0 = sentence[(mg0 & 31) * T_LEN + (mg0 >> 5)];
    const int tok1 = sentence[(mg1 & 31) * T_LEN + (mg1 >> 5)];
    const float* arow0 = embed + (long long)tok0 * EMBD;
    const float* arow1 = embed + (long long)tok1 * EMBD;
    const float* brow0 = Wsrc + (long long)(nOff + m0) * EMBD;
    const float* brow1 = Wsrc + (long long)(nOff + m1) * EMBD;

    float acc[8][8];
#pragma unroll
    for (int i = 0; i < 8; ++i)
#pragma unroll
        for (int j = 0; j < 8; ++j) acc[i][j] = 0.0f;

    for (int k0 = 0; k0 < EMBD; k0 += 16) {
        float4 av0 = *(const float4*)(arow0 + k0 + kq);
        float4 av1 = *(const float4*)(arow1 + k0 + kq);
        float4 bv0 = *(const float4*)(brow0 + k0 + kq);
        float4 bv1 = *(const float4*)(brow1 + k0 + kq);
        __syncthreads();
        As[kq+0][m0] = av0.x; As[kq+1][m0] = av0.y; As[kq+2][m0] = av0.z; As[kq+3][m0] = av0.w;
        As[kq+0][m1] = av1.x; As[kq+1][m1] = av1.y; As[kq+2][m1] = av1.z; As[kq+3][m1] = av1.w;
        Bs[kq+0][m0] = bv0.x; Bs[kq+1][m0] = bv0.y; Bs[kq+2][m0] = bv0.z; Bs[kq+3][m0] = bv0.w;
        Bs[kq+0][m1] = bv1.x; Bs[kq+1][m1] = bv1.y; Bs[kq+2][m1] = bv1.z; Bs[kq+3][m1] = bv1.w;
        __syncthreads();
#pragma unroll
        for (int kt = 0; kt < 16; ++kt) {
            float am[8], bn[8];
            *(float4*)&am[0] = *(const float4*)&As[kt][ty * 4];
            *(float4*)&am[4] = *(const float4*)&As[kt][64 + ty * 4];
            *(float4*)&bn[0] = *(const float4*)&Bs[kt][tx * 4];
            *(float4*)&bn[4] = *(const float4*)&Bs[kt][64 + tx * 4];
#pragma unroll
            for (int i = 0; i < 8; ++i)
#pragma unroll
                for (int j = 0; j < 8; ++j) acc[i][j] += am[i] * bn[j];
        }
    }

    float4 bias0 = *(const float4*)(bsrc + nOff + tx * 4);
    float4 bias1 = *(const float4*)(bsrc + nOff + 64 + tx * 4);
    const float bnv[8] = {bias0.x, bias0.y, bias0.z, bias0.w,
                          bias1.x, bias1.y, bias1.z, bias1.w};
#pragma unroll
    for (int i = 0; i < 8; ++i) {
        const int mg = Mbase + ty * 4 + (i & 3) + ((i >= 4) ? 64 : 0);
        float4 o0 = make_float4(acc[i][0] + bnv[0], acc[i][1] + bnv[1],
                                acc[i][2] + bnv[2], acc[i][3] + bnv[3]);
        float4 o1 = make_float4(acc[i][4] + bnv[4], acc[i][5] + bnv[5],
                                acc[i][6] + bnv[6], acc[i][7] + bnv[7]);
        *(float4*)(zx + (long long)mg * 2048 + Nbase + tx * 4) = o0;
        *(float4*)(zx + (long long)mg * 2048 + Nbase + 64 + tx * 4) = o1;
    }
}

// ---------------------------------------------------------------------------
// Kernel 1b: pack W_hh for the R8 8-row x 16-dim thread tile.
// pack[ sl*65536 + tid*128 + i*16 + m ] = W[d][(g*256+e)*256 + kb*16 + m]
//   where rg = tid>>4, kb = tid&15, r = rg*8+i, g = r>>6, j = r&63,
//         q = sl&3, d = sl>>2, e = q*64+j.
// lstm thread tid reads its 512B chunk contiguously.
// ---------------------------------------------------------------------------
__global__ __launch_bounds__(256) void pack_whh(
    const float* __restrict__ Whf, const float* __restrict__ Whb,
    float* __restrict__ pack)
{
    const int gid = blockIdx.x * 256 + threadIdx.x;   // 0..524287
    const int m   = gid & 15;
    const int i   = (gid >> 4) & 7;
    const int tid = (gid >> 7) & 511;
    const int sl  = gid >> 16;
    const int q = sl & 3, d = sl >> 2;
    const int rg = tid >> 4, kb = tid & 15;
    const int r = rg * 8 + i;
    const int g = r >> 6, j = r & 63;
    const int e = q * 64 + j;
    const float* W = d ? Whb : Whf;
    pack[gid] = W[(g * 256 + e) * 256 + kb * 16 + m];
}

// ---------------------------------------------------------------------------
// Kernel 2: team LSTM, 256 WGs x 512 threads.
// R8 DIAGNOSIS: the invariant ~2us step floor was the LDS pipe: every
// thread re-read a 128-float h-half per step = 256 ds_read_b128/CU/step
// x ~12cy = ~3100cy (m134). Exchange variants (R0==R3) never moved it.
// FIX: thread tile = 8 rows x 16 dims (tid = rg*16+kb; rows rg*8..+8,
// dims kb*16..+16). h read/thread = 4 ds_read_b128 (16 floats), 4-lane
// broadcast, bank-clean via 20-float-padded h blocks -> 32 b128/CU/step.
// k-partials reduced IN-REGISTER via DPP row_shr (16-lane rows == kb
// groups); lanes kb==0 write zS[256]; gate wave reads zS conflict-free.
// W: 128 floats -> AGPRs via ONE-TIME "+a" pin (R7's per-iteration pin
// caused copy storms; one-time is copy-free and remat-proof).
// Exchange/zx-prefetch/barriers identical to R6 (single agent channel).
// ---------------------------------------------------------------------------
__global__ __launch_bounds__(512, 2) void lstm_team(
    const float* __restrict__ zx, const float* __restrict__ pack,
    const float* __restrict__ h0, const float* __restrict__ c0,
    unsigned long long* __restrict__ hx,   // [2 par][2 d][32 b][256 e]
    float* __restrict__ lstm_out)
{
    __shared__ float hS0[320];   // 16 blocks x 20 floats (16 data + 4 pad)
    __shared__ float hS1[320];
    __shared__ float zS[256];    // full W_hh·h dot per gate-row

    const int tid = threadIdx.x;
    const int bx  = (int)blockIdx.x;
    const int b  = ((bx >> 5) & 3) * 8 + (bx & 7);
    const int q  = (bx >> 3) & 3;
    const int d  = (bx >> 7) & 1;
    const int sl = d * 4 + q;
    const int rg = tid >> 4;              // row group (8 rows)
    const int kb = tid & 15;              // 16-dim block

    // --- W tile into registers (coalesced), then one-time AGPR pin ---
    float4 wreg[32];                      // [i row 0..7][c 0..3]
    {
        const float4* wrow = (const float4*)(pack + ((long long)sl << 16)
                                             + tid * 128);
#pragma unroll
        for (int c = 0; c < 32; ++c) wreg[c] = wrow[c];
    }
    PINA4(wreg[0],wreg[1],wreg[2],wreg[3]);
    PINA4(wreg[4],wreg[5],wreg[6],wreg[7]);
    PINA4(wreg[8],wreg[9],wreg[10],wreg[11]);
    PINA4(wreg[12],wreg[13],wreg[14],wreg[15]);
    PINA4(wreg[16],wreg[17],wreg[18],wreg[19]);
    PINA4(wreg[20],wreg[21],wreg[22],wreg[23]);
    PINA4(wreg[24],wreg[25],wreg[26],wreg[27]);
    PINA4(wreg[28],wreg[29],wreg[30],wreg[31]);

    const long long hxbase = (long long)(d * 32 + b) * 256;
    float creg = (tid < 64) ? c0[(d * 32 + b) * 256 + q * 64 + tid] : 0.0f;

    if (tid < 256) hS0[((tid >> 4) * 20) + (tid & 15)] =
        h0[(d * 32 + b) * 256 + tid];
    __syncthreads();

    // zx pipeline: current step's 4 gate pre-activations, one step ahead
    const int zco = d * 1024 + q * 64 + (tid & 63);
    float zv0 = 0.f, zv1 = 0.f, zv2 = 0.f, zv3 = 0.f;
    if (tid < 64) {
        const int t0 = d ? (T_LEN - 1) : 0;
        const float* zr = zx + (long long)(t0 * 32 + b) * 2048 + zco;
        zv0 = zr[0]; zv1 = zr[256]; zv2 = zr[512]; zv3 = zr[768];
    }

    for (int s = 0; s < T_LEN; ++s) {
        const int t = d ? (T_LEN - 1 - s) : s;

        // prefetch NEXT step's zx (full step of latency slack)
        float zn0 = zv0, zn1 = zv1, zn2 = zv2, zn3 = zv3;
        if (tid < 64 && s < T_LEN - 1) {
            const int tn = d ? (T_LEN - 2 - s) : (s + 1);
            const float* zr = zx + (long long)(tn * 32 + b) * 2048 + zco;
            zn0 = zr[0]; zn1 = zr[256]; zn2 = zr[512]; zn3 = zr[768];
        }

        const float* hb = (s & 1) ? hS1 : hS0;
        float*       hN = (s & 1) ? hS0 : hS1;
        const float* hh = hb + kb * 20;     // this thread's 16-dim block

        // --- 8x16 tile dot: 4 b128 h-reads, 128 fma from AGPR-resident W ---
        float acc[8];
#pragma unroll
        for (int i = 0; i < 8; ++i) acc[i] = 0.0f;
#pragma unroll
        for (int c = 0; c < 4; ++c) {
            const float4 hv = *(const float4*)(hh + c * 4);
#pragma unroll
            for (int i = 0; i < 8; ++i) {
                const float4 w = wreg[i * 4 + c];
                acc[i] += w.x * hv.x + w.y * hv.y + w.z * hv.z + w.w * hv.w;
            }
        }
        // --- in-register k-reduction across the 16 kb lanes (DPP) ---
        float r0 = dpp_add16(acc[0]), r1 = dpp_add16(acc[1]);
        float r2 = dpp_add16(acc[2]), r3 = dpp_add16(acc[3]);
        float r4 = dpp_add16(acc[4]), r5 = dpp_add16(acc[5]);
        float r6 = dpp_add16(acc[6]), r7 = dpp_add16(acc[7]);
        if (kb == 0) {
            *(float4*)(zS + rg * 8)     = make_float4(r0, r1, r2, r3);
            *(float4*)(zS + rg * 8 + 4) = make_float4(r4, r5, r6, r7);
        }
        __syncthreads();

        const int parN = (s & 1) ^ 1;
        if (tid < 64) {
            const float zi = zS[tid]       + zv0;
            const float zf = zS[64 + tid]  + zv1;
            const float zg = zS[128 + tid] + zv2;
            const float zo = zS[192 + tid] + zv3;
            const float si = 1.0f / (1.0f + expf(-zi));
            const float sf = 1.0f / (1.0f + expf(-zf));
            const float so = 1.0f / (1.0f + expf(-zo));
            creg = sf * creg + si * tanhf(zg);
            const float hn = so * tanhf(creg);
            const int e = q * 64 + tid;
            hN[(e >> 4) * 20 + (e & 15)] = hn;
            lstm_out[(long long)(t * 32 + b) * 512 + d * 256 + e] = hn;
            __hip_atomic_store(hx + (long long)parN * 16384 + hxbase + e,
                ((unsigned long long)(unsigned)(s + 1) << 32)
                    | (unsigned long long)__float_as_uint(hn),
                __ATOMIC_RELAXED, __HIP_MEMORY_SCOPE_AGENT);
        } else if (s < T_LEN - 1) {
            int e = -1;
            if (tid < 256) { if ((tid >> 6) != q) e = tid; }
            else if (tid < 320) { if (q != 0) e = tid - 256; }
            if (e >= 0) {
                const unsigned long long* slot =
                    hx + (long long)parN * 16384 + hxbase + e;
                unsigned long long v;
                do {
                    v = __hip_atomic_load(slot, __ATOMIC_RELAXED,
                                          __HIP_MEMORY_SCOPE_AGENT);
                } while ((unsigned)(v >> 32) != (unsigned)(s + 1));
                hN[(e >> 4) * 20 + (e & 15)] = __uint_as_float((unsigned)v);
            }
        }
        zv0 = zn0; zv1 = zn1; zv2 = zn2; zv3 = zn3;
        __syncthreads();
    }
}

// ---------------------------------------------------------------------------
// Kernel 3: feats = lstm_out @ W_out^T + b_out
// ---------------------------------------------------------------------------
__global__ __launch_bounds__(256) void feats_kernel(
    const float* __restrict__ lstm_out, const float* __restrict__ W_out,
    const float* __restrict__ b_out, float* __restrict__ feats)
{
    const int gid = blockIdx.x * 256 + threadIdx.x;
    if (gid >= 8192 * NTAGS) return;
    const int row = gid / NTAGS;
    const int tag = gid - row * NTAGS;
    const float4* x = (const float4*)(lstm_out + (long long)row * 512);
    const float4* w = (const float4*)(W_out + (long long)tag * 512);
    float acc = b_out[tag];
#pragma unroll 4
    for (int k = 0; k < 128; ++k) {
        float4 a = x[k], bw = w[k];
        acc += a.x * bw.x + a.y * bw.y + a.z * bw.z + a.w * bw.w;
    }
    const int t = row >> 5, b = row & 31;
    feats[(long long)b * (T_LEN * NTAGS) + t * NTAGS + tag] = acc;
}

// ---------------------------------------------------------------------------
// Kernel 4: Viterbi per batch. 32 WGs x 64 threads.
// ---------------------------------------------------------------------------
__global__ __launch_bounds__(64) void viterbi_kernel(
    const float* __restrict__ feats, const float* __restrict__ trans,
    float* __restrict__ out)
{
    __shared__ float featS[T_LEN * NTAGS];
    __shared__ float transS[NTAGS * NTAGS];
    __shared__ float fvS[NTAGS];
    __shared__ unsigned char bpS[T_LEN][NTAGS];
    __shared__ float pathS[T_LEN];

    const int b = blockIdx.x;
    const int lane = threadIdx.x;

    {
        const float4* src = (const float4*)(feats + (long long)b * (T_LEN * NTAGS));
        float4* dst = (float4*)featS;
        for (int i = lane; i < (T_LEN * NTAGS) / 4; i += 64) dst[i] = src[i];
        for (int i = lane; i < NTAGS * NTAGS; i += 64) transS[i] = trans[i];
    }
    __syncthreads();

    float fv[NTAGS];
#pragma unroll
    for (int p = 0; p < NTAGS; ++p) fv[p] = (p == 10) ? 0.0f : NEGV;

    for (int t = 0; t < T_LEN; ++t) {
        if (lane < NTAGS) {
            float best = -3.4e38f; int bi = 0;
#pragma unroll
            for (int p = 0; p < NTAGS; ++p) {
                const float v = fv[p] + transS[lane * NTAGS + p];
                if (v > best) { best = v; bi = p; }
            }
            bpS[t][lane] = (unsigned char)bi;
            fvS[lane] = best + featS[t * NTAGS + lane];
        }
        __syncthreads();
#pragma unroll
        for (int p = 0; p < NTAGS; ++p) fv[p] = fvS[p];
        __syncthreads();
    }

    if (lane < NTAGS) fvS[lane] = fv[lane] + transS[11 * NTAGS + lane];
    __syncthreads();
    if (lane == 0) {
        float best = -3.4e38f; int bi = 0;
        for (int p = 0; p < NTAGS; ++p) {
            const float v = fvS[p];
            if (v > best) { best = v; bi = p; }
        }
        out[b] = best;
        int cur = bi;
        pathS[T_LEN - 1] = (float)cur;
        for (int tt = T_LEN - 2; tt >= 0; --tt) {
            cur = bpS[tt + 1][cur];
            pathS[tt] = (float)cur;
        }
    }
    __syncthreads();
    float* po = out + BATCH + (long long)b * T_LEN;
    for (int i = lane; i < T_LEN; i += 64) po[i] = pathS[i];
}

// ---------------------------------------------------------------------------
extern "C" void kernel_launch(void* const* d_in, const int* in_sizes, int n_in,
                              void* d_out, int out_size, void* d_ws, size_t ws_size,
                              hipStream_t stream)
{
    (void)in_sizes; (void)n_in; (void)out_size; (void)ws_size;
    const int*   sentence = (const int*)  d_in[0];
    const float* embed    = (const float*)d_in[1];
    const float* W_ih_f   = (const float*)d_in[2];
    const float* W_hh_f   = (const float*)d_in[3];
    const float* b_f      = (const float*)d_in[4];
    const float* W_ih_b   = (const float*)d_in[5];
    const float* W_hh_b   = (const float*)d_in[6];
    const float* b_b      = (const float*)d_in[7];
    const float* W_out    = (const float*)d_in[8];
    const float* b_out    = (const float*)d_in[9];
    const float* trans    = (const float*)d_in[10];
    const float* h0       = (const float*)d_in[11];
    const float* c0       = (const float*)d_in[12];
    float* out = (float*)d_out;

    char* ws = (char*)d_ws;
    float* zx       = (float*)ws; ws += (long long)8192 * 2048 * 4;   // 64 MB
    float* lstm_out = (float*)ws; ws += (long long)8192 * 512 * 4;    // 16 MB
    float* feats    = (float*)ws; ws += BATCH * T_LEN * NTAGS * 4;    // 384 KB
    float* pack     = (float*)ws; ws += (long long)524288 * 4;        // 2 MB
    unsigned long long* hx = (unsigned long long*)ws; ws += 2 * 16384 * 8; // 256 KB
    // hx re-poisoned to 0xAA before every launch -> tags invalid. No memset.

    pack_whh<<<2048, 256, 0, stream>>>(W_hh_f, W_hh_b, pack);
    gemm_zx<<<1024, 256, 0, stream>>>(sentence, embed, W_ih_f, W_ih_b, b_f, b_b, zx);
    lstm_team<<<256, 512, 0, stream>>>(zx, pack, h0, c0, hx, lstm_out);
    feats_kernel<<<384, 256, 0, stream>>>(lstm_out, W_out, b_out, feats);
    viterbi_kernel<<<32, 64, 0, stream>>>(feats, trans, out);
}